// Round 5
// baseline (25.573 us; speedup 1.0000x reference)
//
#include <hip/hip_runtime.h>
#include <hip/hip_bf16.h>

#define L2E 1.4426950408889634f

// Conflict-free replicated sigmoid lerp table (round-4 design, proven):
// 256 cells over [-8,8], float2{val,slope}, 16 interleaved copies.
// Entry i of copy c at tab2[i*16+c] -> banks {2c,2c+1} independent of i.
__device__ __forceinline__ float lutl(const float2* __restrict__ tab2,
                                      unsigned copy, float y) {
    const unsigned iy = (unsigned)y;
    const float    fy = y - (float)iy;
    const float2   vs = tab2[iy * 16u + copy];
    return fmaf(vs.y, fy, vs.x);
}

// sigma via trans pipe; argument pre-scaled: yp = -log2(e) * x
// sigma(x) = 1/(1 + e^-x) = rcp(1 + exp2(yp))   -> v_exp_f32 + v_rcp_f32
__device__ __forceinline__ float sig_t(float yp) {
    return __builtin_amdgcn_rcpf(1.0f + __builtin_amdgcn_exp2f(yp));
}

__global__ __launch_bounds__(256) void lstm_fc_hyb(
    const float4* __restrict__ x4,     // [B] float4 (SEQ=4, INPUT=1)
    const float*  __restrict__ W_ih,   // [8]
    const float*  __restrict__ W_hh,   // [8,2]
    const float*  __restrict__ b_ih,   // [8]
    const float*  __restrict__ b_hh,   // [8]
    const float*  __restrict__ W_fc,   // [1,2]
    const float*  __restrict__ b_fc,   // [1]
    float* __restrict__ out,           // [B]
    int B)
{
    __shared__ float2 tab2[256 * 16];  // 32 KB
    __shared__ float  vtmp[257];
    {
        const int t = threadIdx.x;     // exactly 256 threads
        const float xv = fmaf((float)t, 0.0625f, -8.0f);
        vtmp[t] = sig_t(-L2E * xv);
        if (t == 0) vtmp[256] = sig_t(-L2E * 8.0f);
        __syncthreads();
        const float val = vtmp[t];
        const float slp = vtmp[t + 1] - val;
#pragma unroll
        for (int j = 0; j < 16; ++j) {
            const int c = (t + j) & 15;
            tab2[t * 16 + c] = make_float2(val, slp);
        }
        __syncthreads();
    }

    // Gate order [i,f,g,o] x H=2.  LDS set = {i0,i1,o0,o1} (gates 0,1,6,7)
    // in index space y = 16*x + 128 (in-range [15,241] for |x|<=7, no clamp).
    // Trans set = {f0,f1,g0,g1} (gates 2,3,4,5) in exp2 space:
    // scale -L2E for f (sigma), -2*L2E for g (sigma(2g), tanh(g)=2*sig(2g)-1).
    const int IG[4] = {0, 1, 6, 7};
    const int TG[4] = {2, 3, 4, 5};
    float wsI[4], w0I[4], w1I[4], bbI[4];
    float wsT[4], w0T[4], w1T[4], bbT[4];
#pragma unroll
    for (int k = 0; k < 4; ++k) {
        const int g = IG[k];
        wsI[k] = 16.0f * W_ih[g];
        w0I[k] = 16.0f * W_hh[2 * g];
        w1I[k] = 16.0f * W_hh[2 * g + 1];
        bbI[k] = fmaf(16.0f, b_ih[g] + b_hh[g], 128.0f);
    }
#pragma unroll
    for (int k = 0; k < 4; ++k) {
        const int g = TG[k];
        const float s = (k < 2) ? -L2E : -2.0f * L2E;
        wsT[k] = s * W_ih[g];
        w0T[k] = s * W_hh[2 * g];
        w1T[k] = s * W_hh[2 * g + 1];
        bbT[k] = s * (b_ih[g] + b_hh[g]);
    }
    const float wfc0 = W_fc[0], wfc1 = W_fc[1], bfc = b_fc[0];
    const unsigned copy = threadIdx.x & 15u;

    // 3 independent elements per thread (blocked, coalesced): +50% chains/wave.
    const int base = blockIdx.x * 768 + threadIdx.x;
    int   idx[3];
    bool  ok[3];
    float xs[3][4];
#pragma unroll
    for (int e = 0; e < 3; ++e) {
        idx[e] = base + e * 256;
        ok[e]  = idx[e] < B;
        const float4 v = ok[e] ? x4[idx[e]] : make_float4(0.f, 0.f, 0.f, 0.f);
        xs[e][0] = v.x; xs[e][1] = v.y; xs[e][2] = v.z; xs[e][3] = v.w;
    }

    float h0[3], h1[3], d0[3], d1[3];   // d = 2*c; tanh(c) = 2*sigma(d)-1

    // ---- t = 0 (h = c = 0): f unused ----
#pragma unroll
    for (int e = 0; e < 3; ++e) {
        const float xe = xs[e][0];
        const float si0 = lutl(tab2, copy, fmaf(wsI[0], xe, bbI[0]));
        const float si1 = lutl(tab2, copy, fmaf(wsI[1], xe, bbI[1]));
        const float so0 = lutl(tab2, copy, fmaf(wsI[2], xe, bbI[2]));
        const float so1 = lutl(tab2, copy, fmaf(wsI[3], xe, bbI[3]));
        const float rg0 = sig_t(fmaf(wsT[2], xe, bbT[2]));
        const float rg1 = sig_t(fmaf(wsT[3], xe, bbT[3]));
        d0[e] = si0 * fmaf(4.0f, rg0, -2.0f);     // i * 2*tanh(g)
        d1[e] = si1 * fmaf(4.0f, rg1, -2.0f);
        const float E0 = __builtin_amdgcn_exp2f(-L2E * d0[e]);
        const float E1 = __builtin_amdgcn_exp2f(-L2E * d1[e]);
        const float sd20 = __builtin_amdgcn_rcpf(fmaf(0.5f, E0, 0.5f)); // 2*sig(d)
        const float sd21 = __builtin_amdgcn_rcpf(fmaf(0.5f, E1, 0.5f));
        h0[e] = fmaf(sd20, so0, -so0);            // o * (2*sigma(d) - 1)
        h1[e] = fmaf(sd21, so1, -so1);
    }

    // ---- t = 1..3 ----
#pragma unroll
    for (int t = 1; t < 4; ++t) {
#pragma unroll
        for (int e = 0; e < 3; ++e) {
            const float xe = xs[e][t];
            float yI[4], yT[4];
#pragma unroll
            for (int k = 0; k < 4; ++k)
                yI[k] = fmaf(wsI[k], xe,
                        fmaf(w0I[k], h0[e],
                        fmaf(w1I[k], h1[e], bbI[k])));
#pragma unroll
            for (int k = 0; k < 4; ++k)
                yT[k] = fmaf(wsT[k], xe,
                        fmaf(w0T[k], h0[e],
                        fmaf(w1T[k], h1[e], bbT[k])));
            const float si0 = lutl(tab2, copy, yI[0]);
            const float si1 = lutl(tab2, copy, yI[1]);
            const float so0 = lutl(tab2, copy, yI[2]);
            const float so1 = lutl(tab2, copy, yI[3]);
            const float sf0 = sig_t(yT[0]);
            const float sf1 = sig_t(yT[1]);
            const float rg0 = sig_t(yT[2]);
            const float rg1 = sig_t(yT[3]);
            d0[e] = fmaf(sf0, d0[e], si0 * fmaf(4.0f, rg0, -2.0f));
            d1[e] = fmaf(sf1, d1[e], si1 * fmaf(4.0f, rg1, -2.0f));
            const float E0 = __builtin_amdgcn_exp2f(-L2E * d0[e]);
            const float E1 = __builtin_amdgcn_exp2f(-L2E * d1[e]);
            const float sd20 = __builtin_amdgcn_rcpf(fmaf(0.5f, E0, 0.5f));
            const float sd21 = __builtin_amdgcn_rcpf(fmaf(0.5f, E1, 0.5f));
            h0[e] = fmaf(sd20, so0, -so0);
            h1[e] = fmaf(sd21, so1, -so1);
        }
    }

#pragma unroll
    for (int e = 0; e < 3; ++e)
        if (ok[e])
            out[idx[e]] = fmaf(wfc0, h0[e], fmaf(wfc1, h1[e], bfc));
}

extern "C" void kernel_launch(void* const* d_in, const int* in_sizes, int n_in,
                              void* d_out, int out_size, void* d_ws, size_t ws_size,
                              hipStream_t stream) {
    const float4* x4   = (const float4*)d_in[0];
    const float*  W_ih = (const float*)d_in[1];
    const float*  W_hh = (const float*)d_in[2];
    const float*  b_ih = (const float*)d_in[3];
    const float*  b_hh = (const float*)d_in[4];
    const float*  W_fc = (const float*)d_in[5];
    const float*  b_fc = (const float*)d_in[6];
    float* out = (float*)d_out;

    const int B = out_size;                    // 2,097,152
    const int block = 256;
    const int grid = (B + 767) / 768;          // 3 elems/thread, blocked
    lstm_fc_hyb<<<grid, block, 0, stream>>>(x4, W_ih, W_hh, b_ih, b_hh,
                                            W_fc, b_fc, out, B);
}

// Round 6
// 25.052 us; speedup vs baseline: 1.0208x; 1.0208x over previous
//
#include <hip/hip_runtime.h>
#include <hip/hip_bf16.h>

#define L2E 1.4426950408889634f

// sigma via trans pipe; argument pre-scaled: yp = -log2(e) * x
// sigma(x) = rcp(1 + exp2(yp))  -> v_exp_f32 + v_rcp_f32
__device__ __forceinline__ float sig_t(float yp) {
    return __builtin_amdgcn_rcpf(1.0f + __builtin_amdgcn_exp2f(yp));
}

// 256-cell sigmoid lerp table over [-8,8], float2{val,slope}, 8 interleaved
// copies (16 KB total). Entry i of copy c at tab2[i*8+c] -> dword addr
// 16*i + 2*c: the 8 lanes sharing copy c split across only 2 bank-pairs
// (by i&1) -> ~2-4 dwords/bank ~= the ds_read_b64 minimum, independent of
// the data-dependent index distribution. 16 KB keeps 8 blocks/CU resident
// (32 waves/CU) -- 2x the occupancy of the 32 KB variants.
__device__ __forceinline__ float lutl(const float2* __restrict__ tp, float y) {
    const unsigned iy = (unsigned)y;
    const float    fy = y - (float)iy;
    const float2   vs = tp[iy * 8u];
    return fmaf(vs.y, fy, vs.x);
}

__global__ __launch_bounds__(256) void lstm_fc_v6(
    const float4* __restrict__ x4,     // [B] float4 (SEQ=4, INPUT=1)
    const float*  __restrict__ W_ih,   // [8]
    const float*  __restrict__ W_hh,   // [8,2]
    const float*  __restrict__ b_ih,   // [8]
    const float*  __restrict__ b_hh,   // [8]
    const float*  __restrict__ W_fc,   // [1,2]
    const float*  __restrict__ b_fc,   // [1]
    float* __restrict__ out,           // [B]
    int B)
{
    __shared__ float2 tab2[256 * 8];   // 16 KB
    {
        const int t = threadIdx.x;     // exactly 256 threads
        const float xv = fmaf((float)t, 0.0625f, -8.0f);
        const float v0 = sig_t(-L2E * xv);
        const float v1 = sig_t(-L2E * (xv + 0.0625f));
        const float2 ent = make_float2(v0, v1 - v0);
        // rotated copy index -> writes spread across banks, no 16-way pileup
#pragma unroll
        for (int j = 0; j < 8; ++j)
            tab2[t * 8 + ((t + j) & 7)] = ent;
    }
    __syncthreads();

    // Gate order [i,f,g,o] x H=2.  LDS set = {i0,i1,o0,o1} (gates 0,1,6,7)
    // in index space y = 16*x + 128 (|gate| < 7.5 -> in-range, no clamp).
    // Trans set = {f0,f1,g0,g1} (gates 2,3,4,5) in exp2 space:
    // scale -L2E for f (sigma), -2*L2E for g (tanh(g) = 2*sigma(2g) - 1).
    const int IG[4] = {0, 1, 6, 7};
    const int TG[4] = {2, 3, 4, 5};
    float wsI[4], w0I[4], w1I[4], bbI[4];
    float wsT[4], w0T[4], w1T[4], bbT[4];
#pragma unroll
    for (int k = 0; k < 4; ++k) {
        const int g = IG[k];
        wsI[k] = 16.0f * W_ih[g];
        w0I[k] = 16.0f * W_hh[2 * g];
        w1I[k] = 16.0f * W_hh[2 * g + 1];
        bbI[k] = fmaf(16.0f, b_ih[g] + b_hh[g], 128.0f);
    }
#pragma unroll
    for (int k = 0; k < 4; ++k) {
        const int g = TG[k];
        const float s = (k < 2) ? -L2E : -2.0f * L2E;
        wsT[k] = s * W_ih[g];
        w0T[k] = s * W_hh[2 * g];
        w1T[k] = s * W_hh[2 * g + 1];
        bbT[k] = s * (b_ih[g] + b_hh[g]);
    }
    const float wfc0 = W_fc[0], wfc1 = W_fc[1], bfc = b_fc[0];
    const float2* tp = tab2 + (threadIdx.x & 7u);

    const int half = B >> 1;
    const int tid = blockIdx.x * blockDim.x + threadIdx.x;
    if (tid >= half) return;

    // Two independent elements per thread for ILP on the serial chain.
    const float4 xa = x4[tid];
    const float4 xb = x4[tid + half];
    const float xs[2][4] = {{xa.x, xa.y, xa.z, xa.w}, {xb.x, xb.y, xb.z, xb.w}};

    float h0[2], h1[2], d0[2], d1[2];   // d = 2*c; tanh(c) = 2*sigma(d) - 1

    // ---- t = 0 (h = c = 0): f unused ----
#pragma unroll
    for (int e = 0; e < 2; ++e) {
        const float xe = xs[e][0];
        const float si0 = lutl(tp, fmaf(wsI[0], xe, bbI[0]));
        const float si1 = lutl(tp, fmaf(wsI[1], xe, bbI[1]));
        const float so0 = lutl(tp, fmaf(wsI[2], xe, bbI[2]));
        const float so1 = lutl(tp, fmaf(wsI[3], xe, bbI[3]));
        const float rg0 = sig_t(fmaf(wsT[2], xe, bbT[2]));
        const float rg1 = sig_t(fmaf(wsT[3], xe, bbT[3]));
        d0[e] = si0 * fmaf(4.0f, rg0, -2.0f);     // i * 2*tanh(g)
        d1[e] = si1 * fmaf(4.0f, rg1, -2.0f);
        const float E0 = __builtin_amdgcn_exp2f(-L2E * d0[e]);
        const float E1 = __builtin_amdgcn_exp2f(-L2E * d1[e]);
        const float sd20 = __builtin_amdgcn_rcpf(fmaf(0.5f, E0, 0.5f)); // 2*sig(d)
        const float sd21 = __builtin_amdgcn_rcpf(fmaf(0.5f, E1, 0.5f));
        h0[e] = fmaf(sd20, so0, -so0);            // o * (2*sigma(d) - 1)
        h1[e] = fmaf(sd21, so1, -so1);
    }

    // ---- t = 1..3 ----
#pragma unroll
    for (int t = 1; t < 4; ++t) {
#pragma unroll
        for (int e = 0; e < 2; ++e) {
            const float xe = xs[e][t];
            float yI[4], yT[4];
#pragma unroll
            for (int k = 0; k < 4; ++k)
                yI[k] = fmaf(wsI[k], xe,
                        fmaf(w0I[k], h0[e],
                        fmaf(w1I[k], h1[e], bbI[k])));
#pragma unroll
            for (int k = 0; k < 4; ++k)
                yT[k] = fmaf(wsT[k], xe,
                        fmaf(w0T[k], h0[e],
                        fmaf(w1T[k], h1[e], bbT[k])));
            const float si0 = lutl(tp, yI[0]);
            const float si1 = lutl(tp, yI[1]);
            const float so0 = lutl(tp, yI[2]);
            const float so1 = lutl(tp, yI[3]);
            const float sf0 = sig_t(yT[0]);
            const float sf1 = sig_t(yT[1]);
            const float rg0 = sig_t(yT[2]);
            const float rg1 = sig_t(yT[3]);
            d0[e] = fmaf(sf0, d0[e], si0 * fmaf(4.0f, rg0, -2.0f));
            d1[e] = fmaf(sf1, d1[e], si1 * fmaf(4.0f, rg1, -2.0f));
            const float E0 = __builtin_amdgcn_exp2f(-L2E * d0[e]);
            const float E1 = __builtin_amdgcn_exp2f(-L2E * d1[e]);
            const float sd20 = __builtin_amdgcn_rcpf(fmaf(0.5f, E0, 0.5f));
            const float sd21 = __builtin_amdgcn_rcpf(fmaf(0.5f, E1, 0.5f));
            h0[e] = fmaf(sd20, so0, -so0);
            h1[e] = fmaf(sd21, so1, -so1);
        }
    }

    out[tid]        = fmaf(wfc0, h0[0], fmaf(wfc1, h1[0], bfc));
    out[tid + half] = fmaf(wfc0, h0[1], fmaf(wfc1, h1[1], bfc));
}

extern "C" void kernel_launch(void* const* d_in, const int* in_sizes, int n_in,
                              void* d_out, int out_size, void* d_ws, size_t ws_size,
                              hipStream_t stream) {
    const float4* x4   = (const float4*)d_in[0];
    const float*  W_ih = (const float*)d_in[1];
    const float*  W_hh = (const float*)d_in[2];
    const float*  b_ih = (const float*)d_in[3];
    const float*  b_hh = (const float*)d_in[4];
    const float*  W_fc = (const float*)d_in[5];
    const float*  b_fc = (const float*)d_in[6];
    float* out = (float*)d_out;

    const int B = out_size;                  // 2,097,152
    const int half = B >> 1;
    const int block = 256;
    const int grid = (half + block - 1) / block;   // 4096 blocks, 2 elems/thread
    lstm_fc_v6<<<grid, block, 0, stream>>>(x4, W_ih, W_hh, b_ih, b_hh,
                                           W_fc, b_fc, out, B);
}

// Round 7
// 22.670 us; speedup vs baseline: 1.1281x; 1.1051x over previous
//
#include <hip/hip_runtime.h>
#include <hip/hip_bf16.h>

#define L2E 1.4426950408889634f

// trans-pipe sigmoid, PROLOGUE ONLY (table build)
__device__ __forceinline__ float sig_t(float x) {
    return __builtin_amdgcn_rcpf(1.0f + __builtin_amdgcn_exp2f(-L2E * x));
}

// Conflict-free replicated sigmoid lerp table, 16 KB:
//   256 cells over [-8,8] (+1 pad entry at x=8), float2{val, slope},
//   8 interleaved copies: entry i of copy c at tab2[i*8 + c].
//   Lane l uses copy l&7 -> byte addr iy*64 + 8c -> bank pair {2c,2c+16}
//   selected by iy parity: 8 lanes/copy split ~4/bank = ds_read_b64 minimum,
//   independent of the data-dependent index distribution.
// Index space folded into weights: y = 16*x + 128 (32*x for g-gates).
// Main body contains ZERO transcendental ops (trans ~24 cyc/wave64 measured
// vs VALU 2 -- trans was the wall in rounds 1/5/6).
__device__ __forceinline__ float lutl(const float2* __restrict__ tp, float y) {
    const unsigned iy = (unsigned)y;                 // y > 0 always
    const float    fy = __builtin_amdgcn_fractf(y);  // y - trunc(y), 1 instr
    const float2   vs = tp[iy * 8u];
    return fmaf(vs.y, fy, vs.x);
}

__device__ __forceinline__ float gclamp(float y) {
    return __builtin_amdgcn_fmed3f(y, 0.0f, 255.999f);
}

__global__ __launch_bounds__(256) void lstm_fc_v7(
    const float4* __restrict__ x4,     // [B] float4 (SEQ=4, INPUT=1)
    const float*  __restrict__ W_ih,   // [8]
    const float*  __restrict__ W_hh,   // [8,2]
    const float*  __restrict__ b_ih,   // [8]
    const float*  __restrict__ b_hh,   // [8]
    const float*  __restrict__ W_fc,   // [1,2]
    const float*  __restrict__ b_fc,   // [1]
    float* __restrict__ out,           // [B]
    int B)
{
    __shared__ float2 tab2[257 * 8];   // 16.06 KB -> 8 blocks/CU
    {
        const int t = threadIdx.x;     // exactly 256 threads
        const float xv = fmaf((float)t, 0.0625f, -8.0f);
        const float v0 = sig_t(xv);
        const float v1 = sig_t(xv + 0.0625f);
        const float2 ent = make_float2(v0, v1 - v0);
#pragma unroll
        for (int j = 0; j < 8; ++j)
            tab2[t * 8 + ((t + j) & 7)] = ent;
        if (t == 0) {                  // pad entry 256 (x = 8): d-lookup touches
            const float2 pe = make_float2(v1, 0.0f);   // v1 = sigma(8) here? no:
            // careful: for t==0, v1 = sigma(-7.9375). Recompute:
            const float s8 = sig_t(8.0f);
            const float2 pad = make_float2(s8, 0.0f);
#pragma unroll
            for (int j = 0; j < 8; ++j) tab2[256 * 8 + j] = pad;
            (void)pe;
        }
    }
    __syncthreads();

    // Gate order [i,f,g,o] x H=2: 0,1=i  2,3=f  4,5=g  6,7=o.
    float ws[8], w0[8], w1[8], bb[8];
#pragma unroll
    for (int g = 0; g < 8; ++g) {
        const float s = (g == 4 || g == 5) ? 32.0f : 16.0f;
        ws[g] = s * W_ih[g];
        w0[g] = s * W_hh[2 * g];
        w1[g] = s * W_hh[2 * g + 1];
        bb[g] = fmaf(s, b_ih[g] + b_hh[g], 128.0f);
    }
    const float wfc0 = W_fc[0], wfc1 = W_fc[1], bfc = b_fc[0];
    const float2* tp = tab2 + (threadIdx.x & 7u);

    const int half = B >> 1;
    const int tid = blockIdx.x * blockDim.x + threadIdx.x;
    if (tid >= half) return;

    // Two independent elements per thread for ILP on the serial chain.
    const float4 xa = x4[tid];
    const float4 xb = x4[tid + half];
    const float xs[2][4] = {{xa.x, xa.y, xa.z, xa.w}, {xb.x, xb.y, xb.z, xb.w}};

    float h0[2], h1[2], d0[2], d1[2];   // d = 2*c; tanh(c) = 2*sigma(d) - 1

    // ---- t = 0 (h = c = 0): f unused ----
#pragma unroll
    for (int e = 0; e < 2; ++e) {
        const float xe = xs[e][0];
        const float si0 = lutl(tp, fmaf(ws[0], xe, bb[0]));
        const float si1 = lutl(tp, fmaf(ws[1], xe, bb[1]));
        const float sg0 = lutl(tp, gclamp(fmaf(ws[4], xe, bb[4])));
        const float sg1 = lutl(tp, gclamp(fmaf(ws[5], xe, bb[5])));
        const float so0 = lutl(tp, fmaf(ws[6], xe, bb[6]));
        const float so1 = lutl(tp, fmaf(ws[7], xe, bb[7]));
        d0[e] = si0 * fmaf(4.0f, sg0, -2.0f);      // i * 2*tanh(g)
        d1[e] = si1 * fmaf(4.0f, sg1, -2.0f);
        const float sd0 = lutl(tp, fmaf(d0[e], 16.0f, 128.0f));
        const float sd1 = lutl(tp, fmaf(d1[e], 16.0f, 128.0f));
        const float os0 = so0 * sd0, os1 = so1 * sd1;
        h0[e] = fmaf(2.0f, os0, -so0);             // o * (2*sigma(d) - 1)
        h1[e] = fmaf(2.0f, os1, -so1);
    }

    // ---- t = 1..3 ----
#pragma unroll
    for (int t = 1; t < 4; ++t) {
#pragma unroll
        for (int e = 0; e < 2; ++e) {
            const float xe = xs[e][t];
            float y[8];
#pragma unroll
            for (int g = 0; g < 8; ++g)
                y[g] = fmaf(ws[g], xe,
                       fmaf(w0[g], h0[e],
                       fmaf(w1[g], h1[e], bb[g])));
            const float si0 = lutl(tp, y[0]);
            const float si1 = lutl(tp, y[1]);
            const float sf0 = lutl(tp, y[2]);
            const float sf1 = lutl(tp, y[3]);
            const float sg0 = lutl(tp, gclamp(y[4]));
            const float sg1 = lutl(tp, gclamp(y[5]));
            const float so0 = lutl(tp, y[6]);
            const float so1 = lutl(tp, y[7]);
            d0[e] = fmaf(sf0, d0[e], si0 * fmaf(4.0f, sg0, -2.0f));
            d1[e] = fmaf(sf1, d1[e], si1 * fmaf(4.0f, sg1, -2.0f));
            const float sd0 = lutl(tp, fmaf(d0[e], 16.0f, 128.0f));
            const float sd1 = lutl(tp, fmaf(d1[e], 16.0f, 128.0f));
            const float os0 = so0 * sd0, os1 = so1 * sd1;
            h0[e] = fmaf(2.0f, os0, -so0);
            h1[e] = fmaf(2.0f, os1, -so1);
        }
    }

    out[tid]        = fmaf(wfc0, h0[0], fmaf(wfc1, h1[0], bfc));
    out[tid + half] = fmaf(wfc0, h0[1], fmaf(wfc1, h1[1], bfc));
}

extern "C" void kernel_launch(void* const* d_in, const int* in_sizes, int n_in,
                              void* d_out, int out_size, void* d_ws, size_t ws_size,
                              hipStream_t stream) {
    const float4* x4   = (const float4*)d_in[0];
    const float*  W_ih = (const float*)d_in[1];
    const float*  W_hh = (const float*)d_in[2];
    const float*  b_ih = (const float*)d_in[3];
    const float*  b_hh = (const float*)d_in[4];
    const float*  W_fc = (const float*)d_in[5];
    const float*  b_fc = (const float*)d_in[6];
    float* out = (float*)d_out;

    const int B = out_size;                  // 2,097,152
    const int half = B >> 1;
    const int block = 256;
    const int grid = (half + block - 1) / block;   // 4096 blocks, 2 elems/thread
    lstm_fc_v7<<<grid, block, 0, stream>>>(x4, W_ih, W_hh, b_ih, b_hh,
                                           W_fc, b_fc, out, B);
}